// Round 2
// baseline (676.872 us; speedup 1.0000x reference)
//
#include <hip/hip_runtime.h>

typedef __attribute__((ext_vector_type(8))) short short8;
typedef __attribute__((ext_vector_type(4))) float f32x4;

__device__ __forceinline__ unsigned short f2bf(float f) {
  unsigned int u = __builtin_bit_cast(unsigned int, f);
  u += 0x7fffu + ((u >> 16) & 1u);
  return (unsigned short)(u >> 16);
}
__device__ __forceinline__ float bf2f(unsigned short h) {
  unsigned int u = ((unsigned int)h) << 16;
  return __builtin_bit_cast(float, u);
}

// async global->LDS, 16B per lane; lds dest = wave-uniform base + lane*16
__device__ __forceinline__ void gld16(const unsigned short* g, unsigned short* l) {
  __builtin_amdgcn_global_load_lds(
      (const __attribute__((address_space(1))) unsigned int*)g,
      (__attribute__((address_space(3))) unsigned int*)l, 16, 0, 0);
}

// ---------------- batched cast fp32 -> bf16 ----------------
__global__ __launch_bounds__(256) void cast3_kernel(const float* __restrict__ a, const float* __restrict__ b,
                                                    const float* __restrict__ c, unsigned short* __restrict__ oa,
                                                    unsigned short* __restrict__ ob, unsigned short* __restrict__ oc,
                                                    int n4) {
  int idx = blockIdx.x * 256 + threadIdx.x;
  if (idx >= n4) return;
  const float* in = (blockIdx.y == 0) ? a : (blockIdx.y == 1) ? b : c;
  unsigned short* out = (blockIdx.y == 0) ? oa : (blockIdx.y == 1) ? ob : oc;
  const float4 v = ((const float4*)in)[idx];
  ushort4 o;
  o.x = f2bf(v.x); o.y = f2bf(v.y); o.z = f2bf(v.z); o.w = f2bf(v.w);
  ((ushort4*)out)[idx] = o;
}

// ---------------- transpose + cast (z-batched pair): in (K x N fp32) -> out (N x K bf16) ----------------
__global__ __launch_bounds__(256) void transpose2_kernel(const float* __restrict__ in0, unsigned short* __restrict__ out0,
                                                         const float* __restrict__ in1, unsigned short* __restrict__ out1,
                                                         int K, int N) {
  __shared__ float tile[64][65];
  const float* in = blockIdx.z ? in1 : in0;
  unsigned short* out = blockIdx.z ? out1 : out0;
  const int kb = blockIdx.x * 64, nb = blockIdx.y * 64;
  const int tid = threadIdx.x;
  const int r = tid >> 4;
  const int c = (tid & 15) * 4;
#pragma unroll
  for (int i = 0; i < 4; i++) {
    const float4 v = *(const float4*)(in + (size_t)(kb + r + i * 16) * N + nb + c);
    tile[r + i * 16][c + 0] = v.x;
    tile[r + i * 16][c + 1] = v.y;
    tile[r + i * 16][c + 2] = v.z;
    tile[r + i * 16][c + 3] = v.w;
  }
  __syncthreads();
#pragma unroll
  for (int i = 0; i < 4; i++) {
    int n = r + i * 16;
    ushort4 o;
    o.x = f2bf(tile[c + 0][n]);
    o.y = f2bf(tile[c + 1][n]);
    o.z = f2bf(tile[c + 2][n]);
    o.w = f2bf(tile[c + 3][n]);
    *(ushort4*)(out + (size_t)(nb + n) * K + kb + c) = o;
  }
}

// ---------------- m97-style GEMM: C(MxN) = A(MxK) @ BT(NxK)^T, bf16, global_load_lds staging ----------------
// XCD-aware block swizzle (T1): contiguous chunks of the flattened grid per XCD so B-panels
// (shared by blocks with equal n-tile) stay in one XCD's L2. nwg % 8 == 0 for all launches here.
template <int NF, bool F32OUT>
__global__ __launch_bounds__(256, 2) void gemm_lds(const unsigned short* __restrict__ A0,
                                                   const unsigned short* __restrict__ B0, void* __restrict__ C0,
                                                   const unsigned short* __restrict__ A1,
                                                   const unsigned short* __restrict__ B1, void* __restrict__ C1,
                                                   int M, int N, int K) {
  constexpr int TN = NF * 32;
  __shared__ __align__(16) unsigned short As[128 * 64];
  __shared__ __align__(16) unsigned short Bs[TN * 64];
  const unsigned short* A = blockIdx.z ? A1 : A0;
  const unsigned short* BT = blockIdx.z ? B1 : B0;
  void* C = blockIdx.z ? C1 : C0;

  const int nwg = gridDim.x * gridDim.y;
  const int orig = blockIdx.y * gridDim.x + blockIdx.x;
  const int nid = (orig & 7) * (nwg >> 3) + (orig >> 3);
  const int m0 = (nid % gridDim.x) * 128, n0 = (nid / gridDim.x) * TN;
  const int tid = threadIdx.x;
  const int lane = tid & 63;
  const int w = __builtin_amdgcn_readfirstlane(tid >> 6);
  const int wm = (w & 1) * 64, wn = (w >> 1) * (TN / 2);
  const int lr = lane & 15, kg = lane >> 4;
  const int lrow = lane >> 3;
  const int lseg = (lane & 7) ^ lrow;

  const unsigned short* Abase = A + (size_t)(m0 + w * 8 + lrow) * K + lseg * 8;
  const unsigned short* Bbase = BT + (size_t)(n0 + w * 8 + lrow) * K + lseg * 8;

  f32x4 acc[4][NF] = {};
  for (int k0 = 0; k0 < K; k0 += 64) {
#pragma unroll
    for (int i = 0; i < 4; i++)
      gld16(Abase + (size_t)(32 * i) * K + k0, As + (32 * i + w * 8) * 64);
#pragma unroll
    for (int i = 0; i < NF; i++)
      gld16(Bbase + (size_t)(32 * i) * K + k0, Bs + (32 * i + w * 8) * 64);
    __syncthreads();
#pragma unroll
    for (int ks = 0; ks < 2; ks++) {
      short8 af[4], bfg[NF];
#pragma unroll
      for (int mi = 0; mi < 4; mi++) {
        int row = wm + mi * 16 + lr;
        af[mi] = *(const short8*)(As + row * 64 + ((ks * 4 + kg) ^ (lr & 7)) * 8);
      }
#pragma unroll
      for (int ni = 0; ni < NF; ni++) {
        int row = wn + ni * 16 + lr;
        bfg[ni] = *(const short8*)(Bs + row * 64 + ((ks * 4 + kg) ^ (lr & 7)) * 8);
      }
#pragma unroll
      for (int mi = 0; mi < 4; mi++)
#pragma unroll
        for (int ni = 0; ni < NF; ni++)
          acc[mi][ni] = __builtin_amdgcn_mfma_f32_16x16x32_bf16(af[mi], bfg[ni], acc[mi][ni], 0, 0, 0);
    }
    __syncthreads();
  }
#pragma unroll
  for (int mi = 0; mi < 4; mi++)
#pragma unroll
    for (int ni = 0; ni < NF; ni++)
#pragma unroll
      for (int r2 = 0; r2 < 4; r2++) {
        int m = m0 + wm + mi * 16 + kg * 4 + r2;
        int n = n0 + wn + ni * 16 + lr;
        float v = acc[mi][ni][r2];
        if (F32OUT)
          ((float*)C)[(size_t)m * N + n] = v;
        else
          ((unsigned short*)C)[(size_t)m * N + n] = f2bf(v);
      }
}

// ---------------- RoPE in-place on bf16 projected Q or K (oscale folds 1/sqrt(dk) into Q) ----------------
__global__ __launch_bounds__(256) void rope_kernel(unsigned short* __restrict__ buf, int nheads, int total,
                                                   float oscale) {
  int idx = blockIdx.x * 256 + threadIdx.x;
  if (idx >= total) return;
  int i = idx & 63;
  int h = (idx >> 6) % nheads;
  int row = idx / (64 * nheads);
  int pos = row & 1023;
  float invf = exp2f(-(float)(2 * i) * (13.287712379549449f / 128.f));
  float ang = (float)pos * invf;
  float s, c;
  __sincosf(ang, &s, &c);
  unsigned short* p = buf + (size_t)row * ((size_t)nheads * 128) + h * 128;
  float x1 = bf2f(p[i]), x2 = bf2f(p[i + 64]);
  p[i] = f2bf((x1 * c - x2 * s) * oscale);
  p[i + 64] = f2bf((x2 * c + x1 * s) * oscale);
}

// ---------------- mask -> bitmask: mb[(b*1024+q)*16 + k/64] bit j = (mask[b][q][k0+j] != 0) ----------------
__global__ __launch_bounds__(256) void maskbits_kernel(const float* __restrict__ mask,
                                                       unsigned long long* __restrict__ mb) {
  int idx = blockIdx.x * 256 + threadIdx.x;  // 32768 total
  const float4* p = (const float4*)(mask + (size_t)(idx >> 4) * 1024 + (idx & 15) * 64);
  unsigned long long bits = 0ull;
#pragma unroll
  for (int i = 0; i < 16; i++) {
    float4 v = p[i];
    unsigned int g = (unsigned int)(v.x != 0.f) | ((unsigned int)(v.y != 0.f) << 1) |
                     ((unsigned int)(v.z != 0.f) << 2) | ((unsigned int)(v.w != 0.f) << 3);
    bits |= ((unsigned long long)g) << (i * 4);
  }
  mb[idx] = bits;
}

// ---------------- Flash attention, swapped-QK^T form ----------------
// Each lane owns q-row (q0+lr). QK^T computed as mfma(K_frag, Q_frag) with the K-row permutation
//   kappa(nf, i) = 32*(nf&1) + 8*(i>>2) + 4*(nf>>1) + (i&3)
// so lane (lr,kg)'s owned score set over (nf,r2) is exactly {ks2*32 + kg*8 + j} -- the PV
// A-fragment chunks. P never leaves the lane. K fragments read directly from global (L2-resident).
// Vt swizzle f(d) = ((d&7) ^ ((d>>3)&7)) << 3:
//   - read side: d&7 = lr&7 varies across the b128 read's lanes -> banks spread (was 16-way with d>>3-only)
//   - write side: (d>>3)&7 = tid&7 varies across the write's lanes -> stays 2-way (free)
//   entry c at row d holds k = c ^ f(d); reading 8 entries from kbase^f(d) yields k = kbase..kbase+7.
__global__ __launch_bounds__(256, 4) void flash_kernel(const unsigned short* __restrict__ Q,
                                                       const unsigned short* __restrict__ Kbuf,
                                                       const unsigned short* __restrict__ Vbuf,
                                                       const unsigned long long* __restrict__ Mb,
                                                       unsigned short* __restrict__ Ctx) {
  __shared__ unsigned short Vt[2][128][64];
  const int qb = blockIdx.x, h = blockIdx.y, b = blockIdx.z;
  const int hkv = h >> 2;
  const int tid = threadIdx.x, wave = tid >> 6, lane = tid & 63;
  const int lr = lane & 15, kg = lane >> 4;
  const int q0 = qb * 64 + wave * 16;

  auto stageV = [&](int tt) {
    const int k0s = tt * 64;
    unsigned short(*vt)[64] = Vt[tt & 1];
#pragma unroll
    for (int pass = 0; pass < 2; pass++) {
      int kp = (tid >> 4) * 2 + pass * 32;
      int d0 = (tid & 15) * 8;
      short8 v0 = *(const short8*)(Vbuf + (size_t)(b * 1024 + k0s + kp) * 1024 + hkv * 128 + d0);
      short8 v1 = *(const short8*)(Vbuf + (size_t)(b * 1024 + k0s + kp + 1) * 1024 + hkv * 128 + d0);
#pragma unroll
      for (int j = 0; j < 8; j++) {
        int d = d0 + j;
        int kk = kp ^ (((d & 7) ^ ((d >> 3) & 7)) << 3);
        unsigned int pack = (unsigned int)(unsigned short)v0[j] | ((unsigned int)(unsigned short)v1[j] << 16);
        *(unsigned int*)&vt[d][kk] = pack;
      }
    }
  };

  short8 qf[4];
  {
    const unsigned short* qp = Q + (size_t)(b * 1024 + q0 + lr) * 4096 + h * 128 + kg * 8;
#pragma unroll
    for (int ks = 0; ks < 4; ks++) qf[ks] = *(const short8*)(qp + ks * 32);
  }

  // permuted K row base pointers (per-lane): row kappa(nf, lr)
  const unsigned short* Kp[4];
#pragma unroll
  for (int nf = 0; nf < 4; nf++) {
    int krow = ((nf & 1) << 5) + ((lr >> 2) << 3) + ((nf >> 1) << 2) + (lr & 3);
    Kp[nf] = Kbuf + (size_t)(b * 1024 + krow) * 1024 + hkv * 128 + kg * 8;
  }
  const unsigned long long* mp = Mb + (size_t)(b * 1024 + q0 + lr) * 16;

  f32x4 o[8] = {};
  float mcur = -1e30f, lcur = 0.f;

  stageV(0);

  for (int t = 0; t < 16; t++) {
    // QK^T (swapped): s[nf][r2] = S[q0+lr][k0 + kappa(nf, kg*4+r2)], K straight from L2
    f32x4 s[4] = {};
    __builtin_amdgcn_s_setprio(1);
#pragma unroll
    for (int ks = 0; ks < 4; ks++)
#pragma unroll
      for (int nf = 0; nf < 4; nf++) {
        short8 kf = *(const short8*)(Kp[nf] + (size_t)t * 65536 + ks * 32);
        s[nf] = __builtin_amdgcn_mfma_f32_16x16x32_bf16(kf, qf[ks], s[nf], 0, 0, 0);
      }
    __builtin_amdgcn_s_setprio(0);
    const unsigned long long mbv = mp[t];
    __syncthreads();              // Vt[t&1] staged; prior PV readers of Vt[(t+1)&1] done
    if (t < 15) stageV(t + 1);    // issue next-tile V staging; latency hides under softmax+PV

    // mask + scale (scale pre-folded into Q). Owned bit kappa = ks2*32 + kg*8 + jj.
    const unsigned int m0b = (unsigned int)(mbv >> (kg * 8)) & 0xffu;
    const unsigned int m1b = (unsigned int)(mbv >> (32 + kg * 8)) & 0xffu;
    float sv[4][4];
#pragma unroll
    for (int nf = 0; nf < 4; nf++) {
      const unsigned int mm = (nf & 1) ? m1b : m0b;
#pragma unroll
      for (int r2 = 0; r2 < 4; r2++) {
        int jj = ((nf >> 1) << 2) + r2;
        sv[nf][r2] = ((mm >> jj) & 1u) ? s[nf][r2] : -1e9f;
      }
    }

    // row max: per-lane 16 + cross-kg (lanes lr, lr+16, lr+32, lr+48)
    float rmax = sv[0][0];
#pragma unroll
    for (int nf = 0; nf < 4; nf++)
#pragma unroll
      for (int r2 = 0; r2 < 4; r2++) rmax = fmaxf(rmax, sv[nf][r2]);
    rmax = fmaxf(rmax, __shfl_xor(rmax, 16));
    rmax = fmaxf(rmax, __shfl_xor(rmax, 32));

    // defer-max (T13): only rescale when some row grew by > 8
    if (!__all(rmax - mcur <= 8.0f)) {
      float mnew = fmaxf(mcur, rmax);
      float alpha = __expf(mcur - mnew);
      mcur = mnew;
      lcur *= alpha;
      float abc[4];
#pragma unroll
      for (int r2 = 0; r2 < 4; r2++) abc[r2] = __shfl(alpha, kg * 4 + r2);
#pragma unroll
      for (int nf2 = 0; nf2 < 8; nf2++)
#pragma unroll
        for (int r2 = 0; r2 < 4; r2++) o[nf2][r2] *= abc[r2];
    }

    float rsum = 0.f;
    unsigned short pb[4][4];
#pragma unroll
    for (int nf = 0; nf < 4; nf++)
#pragma unroll
      for (int r2 = 0; r2 < 4; r2++) {
        float p = __expf(sv[nf][r2] - mcur);
        rsum += p;
        pb[nf][r2] = f2bf(p);
      }
    rsum += __shfl_xor(rsum, 16);
    rsum += __shfl_xor(rsum, 32);
    lcur += rsum;

    // PV A-fragments are lane-local: pf[ks2] = {p(nf=ks2, r2=0..3), p(nf=ks2+2, r2=0..3)}
    short8 pf[2];
#pragma unroll
    for (int ks2 = 0; ks2 < 2; ks2++) {
      short8 x;
#pragma unroll
      for (int r2 = 0; r2 < 4; r2++) {
        x[r2] = (short)pb[ks2][r2];
        x[4 + r2] = (short)pb[ks2 + 2][r2];
      }
      pf[ks2] = x;
    }

    const unsigned short(*vt)[64] = Vt[t & 1];
    __builtin_amdgcn_s_setprio(1);
#pragma unroll
    for (int ks2 = 0; ks2 < 2; ks2++)
#pragma unroll
      for (int nf2 = 0; nf2 < 8; nf2++) {
        int d = nf2 * 16 + lr;
        int kk = (ks2 * 32 + kg * 8) ^ (((d & 7) ^ ((d >> 3) & 7)) << 3);
        short8 vf = *(const short8*)&vt[d][kk];
        o[nf2] = __builtin_amdgcn_mfma_f32_16x16x32_bf16(pf[ks2], vf, o[nf2], 0, 0, 0);
      }
    __builtin_amdgcn_s_setprio(0);
  }

  float linv = 1.f / lcur;
  float lbc[4];
#pragma unroll
  for (int r2 = 0; r2 < 4; r2++) lbc[r2] = __shfl(linv, kg * 4 + r2);
#pragma unroll
  for (int nf2 = 0; nf2 < 8; nf2++)
#pragma unroll
    for (int r2 = 0; r2 < 4; r2++) {
      int qq = q0 + kg * 4 + r2;
      int d = nf2 * 16 + lr;
      Ctx[(size_t)(b * 1024 + qq) * 4096 + h * 128 + d] = f2bf(o[nf2][r2] * lbc[r2]);
    }
}

extern "C" void kernel_launch(void* const* d_in, const int* in_sizes, int n_in,
                              void* d_out, int out_size, void* d_ws, size_t ws_size,
                              hipStream_t stream) {
  const float* query = (const float*)d_in[0];
  const float* key   = (const float*)d_in[1];
  const float* value = (const float*)d_in[2];
  const float* mask  = (const float*)d_in[3];
  const float* wq    = (const float*)d_in[4];
  const float* wk    = (const float*)d_in[5];
  const float* wv    = (const float*)d_in[6];
  const float* wo    = (const float*)d_in[7];
  float* out = (float*)d_out;

  char* ws = (char*)d_ws;
  size_t off = 0;
  auto alloc = [&](size_t elems) {
    unsigned short* p = (unsigned short*)(ws + off);
    off += ((elems * 2 + 255) / 256) * 256;
    return p;
  };
  unsigned short* qbf = alloc((size_t)2048 * 4096);
  unsigned short* kbf = alloc((size_t)2048 * 4096);
  unsigned short* vbf = alloc((size_t)2048 * 4096);
  unsigned short* wqT = alloc((size_t)4096 * 4096);
  unsigned short* wkT = alloc((size_t)1024 * 4096);
  unsigned short* wvT = alloc((size_t)1024 * 4096);
  unsigned short* woT = alloc((size_t)4096 * 4096);
  unsigned short* Qb  = alloc((size_t)2048 * 4096);
  unsigned short* Kb  = alloc((size_t)2048 * 1024);
  unsigned short* Vb  = alloc((size_t)2048 * 1024);
  unsigned short* Ctx = qbf;                              // reuse: qbf dead after Q projection
  unsigned long long* mbits = (unsigned long long*)kbf;   // reuse: kbf dead after K projection

  cast3_kernel<<<dim3(8192, 3), 256, 0, stream>>>(query, key, value, qbf, kbf, vbf, 2048 * 4096 / 4);
  transpose2_kernel<<<dim3(64, 64, 2), 256, 0, stream>>>(wq, wqT, wo, woT, 4096, 4096);
  transpose2_kernel<<<dim3(64, 16, 2), 256, 0, stream>>>(wk, wkT, wv, wvT, 4096, 1024);

  // Q projection: 2048x4096x4096
  gemm_lds<4, false><<<dim3(16, 32, 1), 256, 0, stream>>>(qbf, wqT, Qb, qbf, wqT, Qb, 2048, 4096, 4096);
  // K and V projections batched: 2048x1024x4096 each
  gemm_lds<2, false><<<dim3(16, 16, 2), 256, 0, stream>>>(kbf, wkT, Kb, vbf, wvT, Vb, 2048, 1024, 4096);

  // kbf is dead now -> safe to build the mask bitmask in its space
  maskbits_kernel<<<128, 256, 0, stream>>>(mask, mbits);

  rope_kernel<<<(2048 * 32 * 64) / 256, 256, 0, stream>>>(Qb, 32, 2048 * 32 * 64, 0.08838834764831845f);
  rope_kernel<<<(2048 * 8 * 64) / 256, 256, 0, stream>>>(Kb, 8, 2048 * 8 * 64, 1.0f);

  flash_kernel<<<dim3(16, 32, 2), 256, 0, stream>>>(Qb, Kb, Vb, mbits, Ctx);

  // output projection: 2048x4096x4096, fp32 out
  gemm_lds<4, true><<<dim3(16, 32, 1), 256, 0, stream>>>(Ctx, woT, out, Ctx, woT, out, 2048, 4096, 4096);

  (void)in_sizes; (void)n_in; (void)out_size; (void)ws_size;
}

// Round 3
// 591.988 us; speedup vs baseline: 1.1434x; 1.1434x over previous
//
#include <hip/hip_runtime.h>

typedef __attribute__((ext_vector_type(8))) short short8;
typedef __attribute__((ext_vector_type(4))) float f32x4;

__device__ __forceinline__ unsigned short f2bf(float f) {
  unsigned int u = __builtin_bit_cast(unsigned int, f);
  u += 0x7fffu + ((u >> 16) & 1u);
  return (unsigned short)(u >> 16);
}
__device__ __forceinline__ float bf2f(unsigned short h) {
  unsigned int u = ((unsigned int)h) << 16;
  return __builtin_bit_cast(float, u);
}

// async global->LDS, 16B per lane; lds dest = wave-uniform base + lane*16
__device__ __forceinline__ void gld16(const unsigned short* g, unsigned short* l) {
  __builtin_amdgcn_global_load_lds(
      (const __attribute__((address_space(1))) unsigned int*)g,
      (__attribute__((address_space(3))) unsigned int*)l, 16, 0, 0);
}

// ---------------- batched cast fp32 -> bf16 ----------------
__global__ __launch_bounds__(256) void cast3_kernel(const float* __restrict__ a, const float* __restrict__ b,
                                                    const float* __restrict__ c, unsigned short* __restrict__ oa,
                                                    unsigned short* __restrict__ ob, unsigned short* __restrict__ oc,
                                                    int n4) {
  int idx = blockIdx.x * 256 + threadIdx.x;
  if (idx >= n4) return;
  const float* in = (blockIdx.y == 0) ? a : (blockIdx.y == 1) ? b : c;
  unsigned short* out = (blockIdx.y == 0) ? oa : (blockIdx.y == 1) ? ob : oc;
  const float4 v = ((const float4*)in)[idx];
  ushort4 o;
  o.x = f2bf(v.x); o.y = f2bf(v.y); o.z = f2bf(v.z); o.w = f2bf(v.w);
  ((ushort4*)out)[idx] = o;
}

// ---------------- transpose + cast (z-batched pair): in (K x N fp32) -> out (N x K bf16) ----------------
__global__ __launch_bounds__(256) void transpose2_kernel(const float* __restrict__ in0, unsigned short* __restrict__ out0,
                                                         const float* __restrict__ in1, unsigned short* __restrict__ out1,
                                                         int K, int N) {
  __shared__ float tile[64][65];
  const float* in = blockIdx.z ? in1 : in0;
  unsigned short* out = blockIdx.z ? out1 : out0;
  const int kb = blockIdx.x * 64, nb = blockIdx.y * 64;
  const int tid = threadIdx.x;
  const int r = tid >> 4;
  const int c = (tid & 15) * 4;
#pragma unroll
  for (int i = 0; i < 4; i++) {
    const float4 v = *(const float4*)(in + (size_t)(kb + r + i * 16) * N + nb + c);
    tile[r + i * 16][c + 0] = v.x;
    tile[r + i * 16][c + 1] = v.y;
    tile[r + i * 16][c + 2] = v.z;
    tile[r + i * 16][c + 3] = v.w;
  }
  __syncthreads();
#pragma unroll
  for (int i = 0; i < 4; i++) {
    int n = r + i * 16;
    ushort4 o;
    o.x = f2bf(tile[c + 0][n]);
    o.y = f2bf(tile[c + 1][n]);
    o.z = f2bf(tile[c + 2][n]);
    o.w = f2bf(tile[c + 3][n]);
    *(ushort4*)(out + (size_t)(nb + n) * K + kb + c) = o;
  }
}

// ---------------- m97-style GEMM: C(MxN) = A(MxK) @ BT(NxK)^T, bf16, global_load_lds staging ----------------
template <int NF, bool F32OUT>
__global__ __launch_bounds__(256, 2) void gemm_lds(const unsigned short* __restrict__ A0,
                                                   const unsigned short* __restrict__ B0, void* __restrict__ C0,
                                                   const unsigned short* __restrict__ A1,
                                                   const unsigned short* __restrict__ B1, void* __restrict__ C1,
                                                   int M, int N, int K) {
  constexpr int TN = NF * 32;
  __shared__ __align__(16) unsigned short As[128 * 64];
  __shared__ __align__(16) unsigned short Bs[TN * 64];
  const unsigned short* A = blockIdx.z ? A1 : A0;
  const unsigned short* BT = blockIdx.z ? B1 : B0;
  void* C = blockIdx.z ? C1 : C0;

  const int m0 = blockIdx.x * 128, n0 = blockIdx.y * TN;
  const int tid = threadIdx.x;
  const int lane = tid & 63;
  const int w = __builtin_amdgcn_readfirstlane(tid >> 6);
  const int wm = (w & 1) * 64, wn = (w >> 1) * (TN / 2);
  const int lr = lane & 15, kg = lane >> 4;
  const int lrow = lane >> 3;
  const int lseg = (lane & 7) ^ lrow;

  const unsigned short* Abase = A + (size_t)(m0 + w * 8 + lrow) * K + lseg * 8;
  const unsigned short* Bbase = BT + (size_t)(n0 + w * 8 + lrow) * K + lseg * 8;

  f32x4 acc[4][NF] = {};
  for (int k0 = 0; k0 < K; k0 += 64) {
#pragma unroll
    for (int i = 0; i < 4; i++)
      gld16(Abase + (size_t)(32 * i) * K + k0, As + (32 * i + w * 8) * 64);
#pragma unroll
    for (int i = 0; i < NF; i++)
      gld16(Bbase + (size_t)(32 * i) * K + k0, Bs + (32 * i + w * 8) * 64);
    __syncthreads();
#pragma unroll
    for (int ks = 0; ks < 2; ks++) {
      short8 af[4], bfg[NF];
#pragma unroll
      for (int mi = 0; mi < 4; mi++) {
        int row = wm + mi * 16 + lr;
        af[mi] = *(const short8*)(As + row * 64 + ((ks * 4 + kg) ^ (lr & 7)) * 8);
      }
#pragma unroll
      for (int ni = 0; ni < NF; ni++) {
        int row = wn + ni * 16 + lr;
        bfg[ni] = *(const short8*)(Bs + row * 64 + ((ks * 4 + kg) ^ (lr & 7)) * 8);
      }
#pragma unroll
      for (int mi = 0; mi < 4; mi++)
#pragma unroll
        for (int ni = 0; ni < NF; ni++)
          acc[mi][ni] = __builtin_amdgcn_mfma_f32_16x16x32_bf16(af[mi], bfg[ni], acc[mi][ni], 0, 0, 0);
    }
    __syncthreads();
  }
#pragma unroll
  for (int mi = 0; mi < 4; mi++)
#pragma unroll
    for (int ni = 0; ni < NF; ni++)
#pragma unroll
      for (int r2 = 0; r2 < 4; r2++) {
        int m = m0 + wm + mi * 16 + kg * 4 + r2;
        int n = n0 + wn + ni * 16 + lr;
        float v = acc[mi][ni][r2];
        if (F32OUT)
          ((float*)C)[(size_t)m * N + n] = v;
        else
          ((unsigned short*)C)[(size_t)m * N + n] = f2bf(v);
      }
}

// ---------------- RoPE in-place on bf16 projected Q or K (oscale folds 1/sqrt(dk) into Q) ----------------
__global__ __launch_bounds__(256) void rope_kernel(unsigned short* __restrict__ buf, int nheads, int total,
                                                   float oscale) {
  int idx = blockIdx.x * 256 + threadIdx.x;
  if (idx >= total) return;
  int i = idx & 63;
  int h = (idx >> 6) % nheads;
  int row = idx / (64 * nheads);
  int pos = row & 1023;
  float invf = exp2f(-(float)(2 * i) * (13.287712379549449f / 128.f));
  float ang = (float)pos * invf;
  float s, c;
  __sincosf(ang, &s, &c);
  unsigned short* p = buf + (size_t)row * ((size_t)nheads * 128) + h * 128;
  float x1 = bf2f(p[i]), x2 = bf2f(p[i + 64]);
  p[i] = f2bf((x1 * c - x2 * s) * oscale);
  p[i + 64] = f2bf((x2 * c + x1 * s) * oscale);
}

// ---------------- mask -> bitmask: mb[(b*1024+q)*16 + k/64] bit j = (mask[b][q][k0+j] != 0) ----------------
__global__ __launch_bounds__(256) void maskbits_kernel(const float* __restrict__ mask,
                                                       unsigned long long* __restrict__ mb) {
  int idx = blockIdx.x * 256 + threadIdx.x;  // 32768 total
  const float4* p = (const float4*)(mask + (size_t)(idx >> 4) * 1024 + (idx & 15) * 64);
  unsigned long long bits = 0ull;
#pragma unroll
  for (int i = 0; i < 16; i++) {
    float4 v = p[i];
    unsigned int g = (unsigned int)(v.x != 0.f) | ((unsigned int)(v.y != 0.f) << 1) |
                     ((unsigned int)(v.z != 0.f) << 2) | ((unsigned int)(v.w != 0.f) << 3);
    bits |= ((unsigned long long)g) << (i * 4);
  }
  mb[idx] = bits;
}

// ---------------- Flash attention, swapped-QK^T, K staged in LDS via global_load_lds ----------------
// Lane owns q-row (q0+lr). QK^T = mfma(K_frag, Q_frag) with K-row permutation
//   kappa(nf, i) = 32*(nf&1) + 8*(i>>2) + 4*(nf>>1) + (i&3)
// K LDS: row rho = nf*16 + lr holds GLOBAL row kappa(nf, lr); 16B slot s holds global slot s ^ (rho&15)
//   (pre-swizzled global source, linear LDS dest -- gld_lds constraint, rule #21).
//   QK read slot = (ks*4+kg) ^ lr -> 8 distinct 16B starts over 128B -> conflict-free.
// Schedule/tile (2 barriers): loadV(t+1)->regs (issue-early) | QK from LDS | softmax |
//   barrier B | gld16 K(t+1) (async, hides under PV) | PV | writeV(t+1) | barrier A.
__global__ __launch_bounds__(256, 3) void flash_kernel(const unsigned short* __restrict__ Q,
                                                       const unsigned short* __restrict__ Kbuf,
                                                       const unsigned short* __restrict__ Vbuf,
                                                       const unsigned long long* __restrict__ Mb,
                                                       unsigned short* __restrict__ Ctx) {
  __shared__ __align__(16) unsigned short Ks[64 * 128];
  __shared__ __align__(16) unsigned short Vt[2][128][64];
  const int qb = blockIdx.x, h = blockIdx.y, b = blockIdx.z;
  const int hkv = h >> 2;
  const int tid = threadIdx.x, wave = tid >> 6, lane = tid & 63;
  const int lr = lane & 15, kg = lane >> 4;
  const int q0 = qb * 64 + wave * 16;

  // K staging addressing: wave w, chunk i covers LDS rows [16w+4i, 16w+4i+3]
  const unsigned short* ksrc[4];
  unsigned short* kdst[4];
#pragma unroll
  for (int i = 0; i < 4; i++) {
    const int rho = 16 * wave + 4 * i + (lane >> 4);
    const int nf = rho >> 4, l2 = rho & 15;
    const int grow = ((nf & 1) << 5) + ((l2 >> 2) << 3) + ((nf >> 1) << 2) + (l2 & 3);
    const int sb = ((((lane & 15) << 4) ^ (l2 << 4)) >> 1);  // pre-swizzled source offset (shorts)
    ksrc[i] = Kbuf + (size_t)(b * 1024 + grow) * 1024 + hkv * 128 + sb;
    kdst[i] = Ks + (16 * wave + 4 * i) * 128;
  }

  // V staging: reg-staged transpose (same pack/swizzle as before)
  const int vkp = (tid >> 4) * 2;
  const int vd0 = (tid & 15) * 8;
  const unsigned short* vsrc = Vbuf + (size_t)(b * 1024) * 1024 + hkv * 128 + vd0;
  short8 vreg[4];
  auto loadV = [&](int tt) {
    const size_t roff = (size_t)(tt * 64) * 1024;
#pragma unroll
    for (int p = 0; p < 2; p++) {
      vreg[2 * p]     = *(const short8*)(vsrc + roff + (size_t)(vkp + p * 32) * 1024);
      vreg[2 * p + 1] = *(const short8*)(vsrc + roff + (size_t)(vkp + p * 32 + 1) * 1024);
    }
  };
  auto writeV = [&](int tt) {
    unsigned short(*vt)[64] = Vt[tt & 1];
#pragma unroll
    for (int p = 0; p < 2; p++) {
      const int kp = vkp + p * 32;
#pragma unroll
      for (int j = 0; j < 8; j++) {
        const int d = vd0 + j;
        const int kk = kp ^ (((d & 7) ^ ((d >> 3) & 7)) << 3);
        unsigned int pack = (unsigned int)(unsigned short)vreg[2 * p][j] |
                            ((unsigned int)(unsigned short)vreg[2 * p + 1][j] << 16);
        *(unsigned int*)&vt[d][kk] = pack;
      }
    }
  };

  short8 qf[4];
  {
    const unsigned short* qp = Q + (size_t)(b * 1024 + q0 + lr) * 4096 + h * 128 + kg * 8;
#pragma unroll
    for (int ks = 0; ks < 4; ks++) qf[ks] = *(const short8*)(qp + ks * 32);
  }
  const unsigned long long* mp = Mb + (size_t)(b * 1024 + q0 + lr) * 16;

  f32x4 o[8] = {};
  float mcur = -1e30f, lcur = 0.f;

  // prologue: stage K(0) + V(0)
#pragma unroll
  for (int i = 0; i < 4; i++) gld16(ksrc[i], kdst[i]);
  loadV(0);
  writeV(0);
  __syncthreads();

  const int cswz = lr << 4;

  for (int t = 0; t < 16; t++) {
    if (t < 15) loadV(t + 1);  // issue early; consumed after barrier B (T14)

    f32x4 s[4] = {};
    __builtin_amdgcn_s_setprio(1);
#pragma unroll
    for (int ks = 0; ks < 4; ks++)
#pragma unroll
      for (int nf = 0; nf < 4; nf++) {
        const int rho = nf * 16 + lr;
        short8 kf = *(const short8*)(Ks + rho * 128 + (((ks * 64 + kg * 16) ^ cswz) >> 1));
        s[nf] = __builtin_amdgcn_mfma_f32_16x16x32_bf16(kf, qf[ks], s[nf], 0, 0, 0);
      }
    __builtin_amdgcn_s_setprio(0);
    const unsigned long long mbv = mp[t];

    // mask (scale pre-folded into Q). Owned bit kappa = ks2*32 + kg*8 + jj.
    const unsigned int m0b = (unsigned int)(mbv >> (kg * 8)) & 0xffu;
    const unsigned int m1b = (unsigned int)(mbv >> (32 + kg * 8)) & 0xffu;
    float sv[4][4];
#pragma unroll
    for (int nf = 0; nf < 4; nf++) {
      const unsigned int mm = (nf & 1) ? m1b : m0b;
#pragma unroll
      for (int r2 = 0; r2 < 4; r2++) {
        int jj = ((nf >> 1) << 2) + r2;
        sv[nf][r2] = ((mm >> jj) & 1u) ? s[nf][r2] : -1e9f;
      }
    }

    // row max: per-lane 16 + cross-kg
    float rmax = sv[0][0];
#pragma unroll
    for (int nf = 0; nf < 4; nf++)
#pragma unroll
      for (int r2 = 0; r2 < 4; r2++) rmax = fmaxf(rmax, sv[nf][r2]);
    rmax = fmaxf(rmax, __shfl_xor(rmax, 16));
    rmax = fmaxf(rmax, __shfl_xor(rmax, 32));

    // defer-max (T13)
    if (!__all(rmax - mcur <= 8.0f)) {
      float mnew = fmaxf(mcur, rmax);
      float alpha = __expf(mcur - mnew);
      mcur = mnew;
      lcur *= alpha;
      float abc[4];
#pragma unroll
      for (int r2 = 0; r2 < 4; r2++) abc[r2] = __shfl(alpha, kg * 4 + r2);
#pragma unroll
      for (int nf2 = 0; nf2 < 8; nf2++)
#pragma unroll
        for (int r2 = 0; r2 < 4; r2++) o[nf2][r2] *= abc[r2];
    }

    float rsum = 0.f;
    unsigned short pb[4][4];
#pragma unroll
    for (int nf = 0; nf < 4; nf++)
#pragma unroll
      for (int r2 = 0; r2 < 4; r2++) {
        float p = __expf(sv[nf][r2] - mcur);
        rsum += p;
        pb[nf][r2] = f2bf(p);
      }
    rsum += __shfl_xor(rsum, 16);
    rsum += __shfl_xor(rsum, 32);
    lcur += rsum;

    // lane-local PV A-fragments
    short8 pf[2];
#pragma unroll
    for (int ks2 = 0; ks2 < 2; ks2++) {
      short8 x;
#pragma unroll
      for (int r2 = 0; r2 < 4; r2++) {
        x[r2] = (short)pb[ks2][r2];
        x[4 + r2] = (short)pb[ks2 + 2][r2];
      }
      pf[ks2] = x;
    }

    __syncthreads();  // B: all waves finished reading Ks(t)
    if (t < 15) {
#pragma unroll
      for (int i = 0; i < 4; i++) gld16(ksrc[i] + (size_t)(t + 1) * 65536, kdst[i]);  // async, hides under PV
    }

    const unsigned short(*vt)[64] = Vt[t & 1];
    __builtin_amdgcn_s_setprio(1);
#pragma unroll
    for (int ks2 = 0; ks2 < 2; ks2++)
#pragma unroll
      for (int nf2 = 0; nf2 < 8; nf2++) {
        int d = nf2 * 16 + lr;
        int kk = (ks2 * 32 + kg * 8) ^ (((d & 7) ^ ((d >> 3) & 7)) << 3);
        short8 vf = *(const short8*)&vt[d][kk];
        o[nf2] = __builtin_amdgcn_mfma_f32_16x16x32_bf16(pf[ks2], vf, o[nf2], 0, 0, 0);
      }
    __builtin_amdgcn_s_setprio(0);
    if (t < 15) writeV(t + 1);  // vmcnt wait maximally deferred
    __syncthreads();            // A: K(t+1) DMA drained, V(t+1) visible
  }

  float linv = 1.f / lcur;
  float lbc[4];
#pragma unroll
  for (int r2 = 0; r2 < 4; r2++) lbc[r2] = __shfl(linv, kg * 4 + r2);
#pragma unroll
  for (int nf2 = 0; nf2 < 8; nf2++)
#pragma unroll
    for (int r2 = 0; r2 < 4; r2++) {
      int qq = q0 + kg * 4 + r2;
      int d = nf2 * 16 + lr;
      Ctx[(size_t)(b * 1024 + qq) * 4096 + h * 128 + d] = f2bf(o[nf2][r2] * lbc[r2]);
    }
}

extern "C" void kernel_launch(void* const* d_in, const int* in_sizes, int n_in,
                              void* d_out, int out_size, void* d_ws, size_t ws_size,
                              hipStream_t stream) {
  const float* query = (const float*)d_in[0];
  const float* key   = (const float*)d_in[1];
  const float* value = (const float*)d_in[2];
  const float* mask  = (const float*)d_in[3];
  const float* wq    = (const float*)d_in[4];
  const float* wk    = (const float*)d_in[5];
  const float* wv    = (const float*)d_in[6];
  const float* wo    = (const float*)d_in[7];
  float* out = (float*)d_out;

  char* ws = (char*)d_ws;
  size_t off = 0;
  auto alloc = [&](size_t elems) {
    unsigned short* p = (unsigned short*)(ws + off);
    off += ((elems * 2 + 255) / 256) * 256;
    return p;
  };
  unsigned short* qbf = alloc((size_t)2048 * 4096);
  unsigned short* kbf = alloc((size_t)2048 * 4096);
  unsigned short* vbf = alloc((size_t)2048 * 4096);
  unsigned short* wqT = alloc((size_t)4096 * 4096);
  unsigned short* wkT = alloc((size_t)1024 * 4096);
  unsigned short* wvT = alloc((size_t)1024 * 4096);
  unsigned short* woT = alloc((size_t)4096 * 4096);
  unsigned short* Qb  = alloc((size_t)2048 * 4096);
  unsigned short* Kb  = alloc((size_t)2048 * 1024);
  unsigned short* Vb  = alloc((size_t)2048 * 1024);
  unsigned short* Ctx = qbf;                              // reuse: qbf dead after Q projection
  unsigned long long* mbits = (unsigned long long*)kbf;   // reuse: kbf dead after K projection

  cast3_kernel<<<dim3(8192, 3), 256, 0, stream>>>(query, key, value, qbf, kbf, vbf, 2048 * 4096 / 4);
  transpose2_kernel<<<dim3(64, 64, 2), 256, 0, stream>>>(wq, wqT, wo, woT, 4096, 4096);
  transpose2_kernel<<<dim3(64, 16, 2), 256, 0, stream>>>(wk, wkT, wv, wvT, 4096, 1024);

  // Q projection: 2048x4096x4096
  gemm_lds<4, false><<<dim3(16, 32, 1), 256, 0, stream>>>(qbf, wqT, Qb, qbf, wqT, Qb, 2048, 4096, 4096);
  // K and V projections batched: 2048x1024x4096 each
  gemm_lds<2, false><<<dim3(16, 16, 2), 256, 0, stream>>>(kbf, wkT, Kb, vbf, wvT, Vb, 2048, 1024, 4096);

  // kbf is dead now -> safe to build the mask bitmask in its space
  maskbits_kernel<<<128, 256, 0, stream>>>(mask, mbits);

  rope_kernel<<<(2048 * 32 * 64) / 256, 256, 0, stream>>>(Qb, 32, 2048 * 32 * 64, 0.08838834764831845f);
  rope_kernel<<<(2048 * 8 * 64) / 256, 256, 0, stream>>>(Kb, 8, 2048 * 8 * 64, 1.0f);

  flash_kernel<<<dim3(16, 32, 2), 256, 0, stream>>>(Qb, Kb, Vb, mbits, Ctx);

  // output projection: 2048x4096x4096, fp32 out
  gemm_lds<4, true><<<dim3(16, 32, 1), 256, 0, stream>>>(Ctx, woT, out, Ctx, woT, out, 2048, 4096, 4096);

  (void)in_sizes; (void)n_in; (void)out_size; (void)ws_size;
}